// Round 16
// baseline (70.176 us; speedup 1.0000x reference)
//
#include <hip/hip_runtime.h>
#include <hip/hip_bf16.h>
#include <math.h>

typedef __attribute__((ext_vector_type(8))) _Float16 half8;
typedef __attribute__((ext_vector_type(16))) float f32x16;
typedef unsigned int uint;
typedef unsigned short ushort;

#define HWSZ 16384
#define PADW 130
#define SLAB (PADW*PADW*64)
// window: 14 rows x 22 cols of 128B cells at 128B stride (shrunk from 15x23
// to fit 3 blocks/CU; rare out-of-window samples take the exact dirty path).
// chunk q of cell ci stored at slot q ^ hx(ci), hx = (ci ^ (ci>>3)) & 7.
#define WR 14
#define WC 22
#define NCELL (WR*WC)            // 308
#define CSTRIDE 128
#define OMS_OFF (NCELL*CSTRIDE)  // 39424
#define SM_BYTES (OMS_OFF + 4*27*33*4)   // 53680 -> 3 blocks/CU

__device__ __forceinline__ int hx16(int ci) {
    return ((ci ^ (ci >> 3)) & 7) << 4;
}
__device__ __forceinline__ ushort f2hu(float a) {
    _Float16 h = (_Float16)a; return *(ushort*)&h;
}
__device__ __forceinline__ uint pk2h(float a, float b) {
    _Float16 ha = (_Float16)a, hb = (_Float16)b;
    ushort ua = *(ushort*)&ha, ub = *(ushort*)&hb;
    return (uint)ua | ((uint)ub << 16);
}

// packed-fp16 bilinear combine (v_pk_fma_f16)
__device__ __forceinline__ half8 combine4h(half8 a0, half8 a1, half8 a2, half8 a3,
                                           float g0, float g1, float g2, float g3)
{
    _Float16 G0 = (_Float16)g0, G1 = (_Float16)g1;
    _Float16 G2 = (_Float16)g2, G3 = (_Float16)g3;
    return a0 * G0 + a1 * G1 + a2 * G2 + a3 * G3;
}

__device__ __forceinline__ void coords_tap_lds(
    const float* __restrict__ omS, int p, int irow, int jcol, int n,
    int4& cc, float4& bg)
{
    int di = n / 3, dj = n - di * 3;
    float offx = omS[n * 33 + p];
    float offy = omS[(9 + n) * 33 + p];
    float mv   = omS[(18 + n) * 33 + p];
    float pxf = (float)(irow + di) + offx;
    float pyf = (float)(jcol + dj) + offy;
    float fx = floorf(pxf), fy = floorf(pyf);
    float qltx = fminf(fmaxf(fx,       0.f), 129.f);
    float qlty = fminf(fmaxf(fy,       0.f), 129.f);
    float qrbx = fminf(fmaxf(fx + 1.f, 0.f), 129.f);
    float qrby = fminf(fmaxf(fy + 1.f, 0.f), 129.f);
    float pxc  = fminf(fmaxf(pxf,      0.f), 129.f);
    float pyc  = fminf(fmaxf(pyf,      0.f), 129.f);
    float glt = (1.f + (qltx - pxc)) * (1.f + (qlty - pyc));
    float grb = (1.f - (qrbx - pxc)) * (1.f - (qrby - pyc));
    float glb = (1.f + (qltx - pxc)) * (1.f - (qrby - pyc));
    float grt = (1.f - (qrbx - pxc)) * (1.f + (qlty - pyc));
    cc.x = (int)qltx; cc.y = (int)qlty; cc.z = (int)qrbx; cc.w = (int)qrby;
    bg.x = glt * mv; bg.y = grb * mv; bg.z = glb * mv; bg.w = grt * mv;
}

// ---------------------------------------------------------------------------
// prep: blocks [0,432): fragment-major fp16 weight buffers
//       blocks [432,560): NCHW fp32 -> padded NHWC fp16
//       blocks [560,1592): zero borders of xt and y1t
// ---------------------------------------------------------------------------
__global__ __launch_bounds__(256, 2) void prep(
    const float* __restrict__ x, ushort* __restrict__ xtt, ushort* __restrict__ y1t,
    const float* __restrict__ wc1, const float* __restrict__ wp1, const float* __restrict__ wm1,
    const float* __restrict__ wc2, const float* __restrict__ wp2, const float* __restrict__ wm2,
    ushort* __restrict__ wdf1, ushort* __restrict__ wof1,
    ushort* __restrict__ wdf2, ushort* __restrict__ wof2)
{
    int t = threadIdx.x;
    if (blockIdx.x < 432) {
        int idx0 = blockIdx.x * 256 + t;
        if (idx0 < 73728) {
            int lay = idx0 >= 36864;
            int idx = idx0 - lay * 36864;
            const float* wc = lay ? wc2 : wc1;
            ushort* dst = lay ? wdf2 : wdf1;
            int j = idx & 7, l = (idx >> 3) & 63;
            int nt = (idx >> 9) & 1, kb = (idx >> 10) & 3, tap = idx >> 12;
            int oc = nt * 32 + (l & 31);
            int c  = kb * 16 + ((l >> 5) << 3) + j;
            dst[idx] = f2hu(wc[(oc * 64 + c) * 9 + tap]);
        } else if (idx0 < 110592) {
            int r = idx0 - 73728;
            int lay = r >= 18432;
            int idx = r - lay * 18432;
            const float* wp = lay ? wp2 : wp1;
            const float* wm = lay ? wm2 : wm1;
            ushort* dst = lay ? wof2 : wof1;
            int j = idx & 7, l = (idx >> 3) & 63;
            int kb = (idx >> 9) & 3, tap = idx >> 11;
            int ch = l & 31;
            int c  = kb * 16 + ((l >> 5) << 3) + j;
            float v = 0.f;
            if (ch < 18)      v = wp[(ch * 64 + c) * 9 + tap];
            else if (ch < 27) v = wm[((ch - 18) * 64 + c) * 9 + tap];
            dst[idx] = f2hu(v);
        }
        return;
    }
    int bx = blockIdx.x - 432;
    int l = t & 63, wv = t >> 6;
    if (bx < 128) {
        int c2 = l & 31, ps = l >> 5;
        int pix0w = bx * 512 + wv * 128;
        int bq = pix0w >> 14;
        const float* xp0 = x + ((size_t)(bq * 64 + c2 * 2)) * HWSZ;
        ushort* xw = xtt + (size_t)bq * SLAB;
        #pragma unroll 8
        for (int p = 0; p < 64; ++p) {
            int pxi = (pix0w + p * 2 + ps) & (HWSZ - 1);
            int i = pxi >> 7, j = pxi & 127;
            uint u = pk2h(xp0[pxi], xp0[pxi + HWSZ]);
            *(uint*)(xw + ((i + 1) * PADW + (j + 1)) * 64 + c2 * 2) = u;
        }
    } else {
        int idx = (bx - 128) * 256 + t;
        if (idx >= 264192) return;
        ushort* buf = (idx >= 132096) ? y1t : xtt;
        int e_all = idx % 132096;
        int bq = e_all / 33024, e = e_all % 33024;
        int i, j, c;
        if (e < 8320)       { i = 0;   j = e >> 6; c = e & 63; }
        else if (e < 16640) { int e2 = e - 8320; i = 129; j = e2 >> 6; c = e2 & 63; }
        else                { int e2 = e - 16640; c = e2 & 63;
                              i = (e2 >> 7) + 1; j = ((e2 >> 6) & 1) ? 129 : 0; }
        buf[(size_t)bq * SLAB + (i * PADW + j) * 64 + c] = 0;
    }
}

// ---------------------------------------------------------------------------
// Fused layer, 32x32x16 fp16 MFMA, CSTRIDE-128 XOR-swizzled 14x22 window,
// 3 blocks/CU. 256 thr / 4 waves; 8x16-px patch; wave owns 32 px.
// ---------------------------------------------------------------------------
#define MF32(a,b,c) __builtin_amdgcn_mfma_f32_32x32x16_f16(a,b,c,0,0,0)

__global__ __launch_bounds__(256, 3) void fused(
    const ushort* __restrict__ xt, const ushort* __restrict__ wof,
    const float* __restrict__ bp, const float* __restrict__ bm,
    const ushort* __restrict__ wdf, const float* __restrict__ xres,
    float* __restrict__ outn, ushort* __restrict__ y1t, int mode)
{
    __shared__ __align__(16) char sm[SM_BYTES];
    const int t = threadIdx.x, l = t & 63, wv = t >> 6;
    const int lb = (blockIdx.x & 7) * 64 + (blockIdx.x >> 3);
    const int bb = lb >> 7;
    const int patch = lb & 127;
    const int i0 = (patch >> 3) * 8;
    const int j0 = (patch & 7) * 16;
    const int p  = l & 31;                   // lane's pixel
    const int h5 = l >> 5;                   // lane's k-half
    const ushort* xb = xt + (size_t)bb * SLAB;
    const char* xbb = (const char*)xb;

    // ---------- stage window (XOR chunk swizzle) ----------
    for (int s = t; s < NCELL * 8; s += 256) {
        int q = s & 7, cq = s >> 3;
        int c = cq % WC, r = cq / WC;
        int ip = min(max(i0 - 2 + r, 0), 129);
        int jp = min(max(j0 - 2 + c, 0), 129);
        uint4 v = *(const uint4*)(xbb + ((ip * PADW + jp) << 7) + (q << 4));
        *(uint4*)(sm + cq * CSTRIDE + ((q << 4) ^ hx16(cq))) = v;
    }
    __syncthreads();

    // ---------- phase 1: offset/mask conv (N=32, 36 MFMA) ----------
    f32x16 oacc = {0.f,0.f,0.f,0.f,0.f,0.f,0.f,0.f,0.f,0.f,0.f,0.f,0.f,0.f,0.f,0.f};
    {
        const int rbase = 2 * wv + (p >> 4) + 2;
        const int cbase = (p & 15) + 2;
        #pragma unroll
        for (int tap = 0; tap < 9; ++tap) {
            int ti = tap / 3, tj = tap - ti * 3;
            int ci = (rbase + ti) * WC + cbase + tj;
            const char* cell = sm + ci * CSTRIDE;
            int hb = hx16(ci);
            #pragma unroll
            for (int kb = 0; kb < 4; ++kb) {
                half8 b = *(const half8*)(wof + ((tap * 4 + kb) * 64 + l) * 8);
                half8 a = *(const half8*)(cell + (((kb * 2 + h5) << 4) ^ hb));
                oacc = MF32(a, b, oacc);
            }
        }
    }
    float* omS = (float*)(sm + OMS_OFF) + wv * 891;   // [27][33] per wave
    {
        int ch = l & 31;
        if (ch < 27) {
            float bias = (ch < 18) ? bp[ch] : bm[ch - 18];
            #pragma unroll
            for (int reg = 0; reg < 16; ++reg) {
                int m = (reg & 3) + 8 * (reg >> 2) + 4 * h5;
                float v = oacc[reg] + bias;
                if (ch >= 18) v = 1.f / (1.f + __expf(-v));
                omS[ch * 33 + m] = v;
            }
        }
    }

    // ---------- phase 2: coords pass, then wave-uniform branch ----------
    f32x16 acc0 = {0.f,0.f,0.f,0.f,0.f,0.f,0.f,0.f,0.f,0.f,0.f,0.f,0.f,0.f,0.f,0.f};
    f32x16 acc1 = acc0;
    const int irow = i0 + 2 * wv + (p >> 4), jcol = j0 + (p & 15);
    uint cpack[9]; float4 gw[9];
    bool okall = true;
    #pragma unroll
    for (int n = 0; n < 9; ++n) {
        int4 cc; float4 g;
        coords_tap_lds(omS, p, irow, jcol, n, cc, g);
        int rlt = cc.x - (i0 - 2), clt = cc.y - (j0 - 2);
        int rrb = cc.z - (i0 - 2), crb = cc.w - (j0 - 2);
        okall = okall & ((uint)rlt < (uint)WR) & ((uint)rrb < (uint)WR) &
                        ((uint)clt < (uint)WC) & ((uint)crb < (uint)WC);
        cpack[n] = (uint)(rlt & 255) | ((uint)(clt & 255) << 8) |
                   ((uint)(rrb & 255) << 16) | ((uint)(crb & 255) << 24);
        gw[n] = g;
    }

    if (__all(okall)) {
        #pragma unroll
        for (int n = 0; n < 9; ++n) {
            uint cp_ = cpack[n];
            int rlt = cp_ & 255, clt = (cp_ >> 8) & 255;
            int rrb = (cp_ >> 16) & 255, crb = cp_ >> 24;
            int ciLT = rlt * WC + clt, ciRB = rrb * WC + crb;
            int ciLB = rlt * WC + crb, ciRT = rrb * WC + clt;
            const char* bLT = sm + ciLT * CSTRIDE;
            const char* bRB = sm + ciRB * CSTRIDE;
            const char* bLB = sm + ciLB * CSTRIDE;
            const char* bRT = sm + ciRT * CSTRIDE;
            int hLT = hx16(ciLT), hRB = hx16(ciRB);
            int hLB = hx16(ciLB), hRT = hx16(ciRT);
            float4 g = gw[n];
            const ushort* wb = wdf + (size_t)n * 4096 + l * 8;
            #pragma unroll
            for (int kb = 0; kb < 4; ++kb) {
                int qo = (kb * 2 + h5) << 4;
                half8 w0 = *(const half8*)(wb + (kb * 2 + 0) * 512);
                half8 w1 = *(const half8*)(wb + (kb * 2 + 1) * 512);
                half8 sLT = *(const half8*)(bLT + (qo ^ hLT));
                half8 sRB = *(const half8*)(bRB + (qo ^ hRB));
                half8 sLB = *(const half8*)(bLB + (qo ^ hLB));
                half8 sRT = *(const half8*)(bRT + (qo ^ hRT));
                half8 a = combine4h(sLT, sRB, sLB, sRT, g.x, g.y, g.z, g.w);
                acc0 = MF32(a, w0, acc0);
                acc1 = MF32(a, w1, acc1);
            }
        }
    } else {
        // dirty path: exact per-tap fallback (rare)
        #pragma unroll
        for (int n = 0; n < 9; ++n) {
            int4 cc; float4 g;
            coords_tap_lds(omS, p, irow, jcol, n, cc, g);
            int rlt = cc.x - (i0 - 2), clt = cc.y - (j0 - 2);
            int rrb = cc.z - (i0 - 2), crb = cc.w - (j0 - 2);
            bool ok = ((uint)rlt < (uint)WR) & ((uint)rrb < (uint)WR) &
                      ((uint)clt < (uint)WC) & ((uint)crb < (uint)WC);
            const ushort* wb = wdf + (size_t)n * 4096 + l * 8;
            #pragma unroll
            for (int kb = 0; kb < 4; ++kb) {
                int qo = (kb * 2 + h5) << 4;
                half8 w0 = *(const half8*)(wb + (kb * 2 + 0) * 512);
                half8 w1 = *(const half8*)(wb + (kb * 2 + 1) * 512);
                half8 sLT, sRB, sLB, sRT;
                if (ok) {
                    int ciLT = rlt * WC + clt, ciRB = rrb * WC + crb;
                    int ciLB = rlt * WC + crb, ciRT = rrb * WC + clt;
                    sLT = *(const half8*)(sm + ciLT * CSTRIDE + (qo ^ hx16(ciLT)));
                    sRB = *(const half8*)(sm + ciRB * CSTRIDE + (qo ^ hx16(ciRB)));
                    sLB = *(const half8*)(sm + ciLB * CSTRIDE + (qo ^ hx16(ciLB)));
                    sRT = *(const half8*)(sm + ciRT * CSTRIDE + (qo ^ hx16(ciRT)));
                } else {
                    sLT = *(const half8*)(xbb + (((cc.x * PADW + cc.y) << 7) + qo));
                    sRB = *(const half8*)(xbb + (((cc.z * PADW + cc.w) << 7) + qo));
                    sLB = *(const half8*)(xbb + (((cc.x * PADW + cc.w) << 7) + qo));
                    sRT = *(const half8*)(xbb + (((cc.z * PADW + cc.y) << 7) + qo));
                }
                half8 a = combine4h(sLT, sRB, sLB, sRT, g.x, g.y, g.z, g.w);
                acc0 = MF32(a, w0, acc0);
                acc1 = MF32(a, w1, acc1);
            }
        }
    }

    // ---------- epilogue ----------
    if (mode == 0) {
        #pragma unroll
        for (int nt = 0; nt < 2; ++nt) {
            int oc = nt * 32 + (l & 31);
            const f32x16& av = nt ? acc1 : acc0;
            #pragma unroll
            for (int qd = 0; qd < 4; ++qd) {
                int m0 = 8 * qd + 4 * h5;
                int lr = m0 >> 4, col0 = m0 & 15;
                size_t o = ((size_t)(bb * 64 + oc)) * HWSZ +
                           (i0 + 2 * wv + lr) * 128 + j0 + col0;
                float4 rsd = *(const float4*)(xres + o);
                float4 vv;
                vv.x = av[qd * 4 + 0] + rsd.x; vv.y = av[qd * 4 + 1] + rsd.y;
                vv.z = av[qd * 4 + 2] + rsd.z; vv.w = av[qd * 4 + 3] + rsd.w;
                *(float4*)(outn + o) = vv;
            }
        }
    } else {
        // relu -> padded NHWC fp16, direct stores (lanes 0-31 = consecutive oc)
        ushort* yb = y1t + (size_t)bb * SLAB;
        #pragma unroll
        for (int nt = 0; nt < 2; ++nt) {
            int oc = nt * 32 + (l & 31);
            const f32x16& av = nt ? acc1 : acc0;
            #pragma unroll
            for (int reg = 0; reg < 16; ++reg) {
                int m = (reg & 3) + 8 * (reg >> 2) + 4 * h5;
                int ip = i0 + 2 * wv + (m >> 4) + 1;
                int jp = j0 + (m & 15) + 1;
                yb[(ip * PADW + jp) * 64 + oc] = f2hu(fmaxf(av[reg], 0.f));
            }
        }
    }
}

// ---------------------------------------------------------------------------
extern "C" void kernel_launch(void* const* d_in, const int* in_sizes, int n_in,
                              void* d_out, int out_size, void* d_ws, size_t ws_size,
                              hipStream_t stream)
{
    const float* x      = (const float*)d_in[0];
    const float* d1_w_p = (const float*)d_in[1];
    const float* d1_b_p = (const float*)d_in[2];
    const float* d1_w_m = (const float*)d_in[3];
    const float* d1_b_m = (const float*)d_in[4];
    const float* d1_w_c = (const float*)d_in[5];
    const float* d2_w_p = (const float*)d_in[6];
    const float* d2_b_p = (const float*)d_in[7];
    const float* d2_w_m = (const float*)d_in[8];
    const float* d2_b_m = (const float*)d_in[9];
    const float* d2_w_c = (const float*)d_in[10];
    float* out = (float*)d_out;

    char* ws = (char*)d_ws;
    ushort* xtt  = (ushort*)(ws);               //  8,652,800 B padded NHWC fp16 x
    ushort* y1t  = (ushort*)(ws + 8652800);     //  8,652,800 B padded NHWC fp16 y1
    ushort* wdf1 = (ushort*)(ws + 17305600);
    ushort* wof1 = (ushort*)(ws + 17379328);
    ushort* wdf2 = (ushort*)(ws + 17416192);
    ushort* wof2 = (ushort*)(ws + 17489920);

    prep<<<1592, 256, 0, stream>>>(x, xtt, y1t,
                                   d1_w_c, d1_w_p, d1_w_m, d2_w_c, d2_w_p, d2_w_m,
                                   wdf1, wof1, wdf2, wof2);

    fused<<<512, 256, 0, stream>>>(xtt, wof1, d1_b_p, d1_b_m, wdf1,
                                   nullptr, nullptr, y1t, 1);
    fused<<<512, 256, 0, stream>>>(y1t, wof2, d2_b_p, d2_b_m, wdf2,
                                   x, out, nullptr, 0);
}

// Round 17
// 63.542 us; speedup vs baseline: 1.1044x; 1.1044x over previous
//
#include <hip/hip_runtime.h>
#include <hip/hip_bf16.h>
#include <math.h>

typedef __attribute__((ext_vector_type(8))) _Float16 half8;
typedef __attribute__((ext_vector_type(16))) float f32x16;
typedef unsigned int uint;
typedef unsigned short ushort;

#define HWSZ 16384
#define PADW 130
#define SLAB (PADW*PADW*64)
// window: 15 rows x 23 cols of 128B cells at 128B stride (R15 geometry —
// R16's 14x22 shrink cut the far-side margin to +1 cell and made the
// whole-wave dirty path frequent: 63.6 -> 70.2 us. Keep +/-2 margins.)
// chunk q of cell ci stored at slot q ^ hx(ci), hx = (ci ^ (ci>>3)) & 7.
#define WR 15
#define WC 23
#define NCELL (WR*WC)            // 345
#define CSTRIDE 128
#define OMS_OFF (NCELL*CSTRIDE)  // 44160
#define SM_BYTES (OMS_OFF + 4*27*33*4)   // 58416

__device__ __forceinline__ int hx16(int ci) {
    return ((ci ^ (ci >> 3)) & 7) << 4;
}
__device__ __forceinline__ ushort f2hu(float a) {
    _Float16 h = (_Float16)a; return *(ushort*)&h;
}
__device__ __forceinline__ uint pk2h(float a, float b) {
    _Float16 ha = (_Float16)a, hb = (_Float16)b;
    ushort ua = *(ushort*)&ha, ub = *(ushort*)&hb;
    return (uint)ua | ((uint)ub << 16);
}

// packed-fp16 bilinear combine (v_pk_fma_f16)
__device__ __forceinline__ half8 combine4h(half8 a0, half8 a1, half8 a2, half8 a3,
                                           float g0, float g1, float g2, float g3)
{
    _Float16 G0 = (_Float16)g0, G1 = (_Float16)g1;
    _Float16 G2 = (_Float16)g2, G3 = (_Float16)g3;
    return a0 * G0 + a1 * G1 + a2 * G2 + a3 * G3;
}

__device__ __forceinline__ void coords_tap_lds(
    const float* __restrict__ omS, int p, int irow, int jcol, int n,
    int4& cc, float4& bg)
{
    int di = n / 3, dj = n - di * 3;
    float offx = omS[n * 33 + p];
    float offy = omS[(9 + n) * 33 + p];
    float mv   = omS[(18 + n) * 33 + p];
    float pxf = (float)(irow + di) + offx;
    float pyf = (float)(jcol + dj) + offy;
    float fx = floorf(pxf), fy = floorf(pyf);
    float qltx = fminf(fmaxf(fx,       0.f), 129.f);
    float qlty = fminf(fmaxf(fy,       0.f), 129.f);
    float qrbx = fminf(fmaxf(fx + 1.f, 0.f), 129.f);
    float qrby = fminf(fmaxf(fy + 1.f, 0.f), 129.f);
    float pxc  = fminf(fmaxf(pxf,      0.f), 129.f);
    float pyc  = fminf(fmaxf(pyf,      0.f), 129.f);
    float glt = (1.f + (qltx - pxc)) * (1.f + (qlty - pyc));
    float grb = (1.f - (qrbx - pxc)) * (1.f - (qrby - pyc));
    float glb = (1.f + (qltx - pxc)) * (1.f - (qrby - pyc));
    float grt = (1.f - (qrbx - pxc)) * (1.f + (qlty - pyc));
    cc.x = (int)qltx; cc.y = (int)qlty; cc.z = (int)qrbx; cc.w = (int)qrby;
    bg.x = glt * mv; bg.y = grb * mv; bg.z = glb * mv; bg.w = grt * mv;
}

// ---------------------------------------------------------------------------
// prep: blocks [0,432): fragment-major fp16 weight buffers
//       blocks [432,560): NCHW fp32 -> padded NHWC fp16
//       blocks [560,1592): zero borders of xt and y1t
// ---------------------------------------------------------------------------
__global__ __launch_bounds__(256, 2) void prep(
    const float* __restrict__ x, ushort* __restrict__ xtt, ushort* __restrict__ y1t,
    const float* __restrict__ wc1, const float* __restrict__ wp1, const float* __restrict__ wm1,
    const float* __restrict__ wc2, const float* __restrict__ wp2, const float* __restrict__ wm2,
    ushort* __restrict__ wdf1, ushort* __restrict__ wof1,
    ushort* __restrict__ wdf2, ushort* __restrict__ wof2)
{
    int t = threadIdx.x;
    if (blockIdx.x < 432) {
        int idx0 = blockIdx.x * 256 + t;
        if (idx0 < 73728) {
            int lay = idx0 >= 36864;
            int idx = idx0 - lay * 36864;
            const float* wc = lay ? wc2 : wc1;
            ushort* dst = lay ? wdf2 : wdf1;
            int j = idx & 7, l = (idx >> 3) & 63;
            int nt = (idx >> 9) & 1, kb = (idx >> 10) & 3, tap = idx >> 12;
            int oc = nt * 32 + (l & 31);
            int c  = kb * 16 + ((l >> 5) << 3) + j;
            dst[idx] = f2hu(wc[(oc * 64 + c) * 9 + tap]);
        } else if (idx0 < 110592) {
            int r = idx0 - 73728;
            int lay = r >= 18432;
            int idx = r - lay * 18432;
            const float* wp = lay ? wp2 : wp1;
            const float* wm = lay ? wm2 : wm1;
            ushort* dst = lay ? wof2 : wof1;
            int j = idx & 7, l = (idx >> 3) & 63;
            int kb = (idx >> 9) & 3, tap = idx >> 11;
            int ch = l & 31;
            int c  = kb * 16 + ((l >> 5) << 3) + j;
            float v = 0.f;
            if (ch < 18)      v = wp[(ch * 64 + c) * 9 + tap];
            else if (ch < 27) v = wm[((ch - 18) * 64 + c) * 9 + tap];
            dst[idx] = f2hu(v);
        }
        return;
    }
    int bx = blockIdx.x - 432;
    int l = t & 63, wv = t >> 6;
    if (bx < 128) {
        int c2 = l & 31, ps = l >> 5;
        int pix0w = bx * 512 + wv * 128;
        int bq = pix0w >> 14;
        const float* xp0 = x + ((size_t)(bq * 64 + c2 * 2)) * HWSZ;
        ushort* xw = xtt + (size_t)bq * SLAB;
        #pragma unroll 8
        for (int p = 0; p < 64; ++p) {
            int pxi = (pix0w + p * 2 + ps) & (HWSZ - 1);
            int i = pxi >> 7, j = pxi & 127;
            uint u = pk2h(xp0[pxi], xp0[pxi + HWSZ]);
            *(uint*)(xw + ((i + 1) * PADW + (j + 1)) * 64 + c2 * 2) = u;
        }
    } else {
        int idx = (bx - 128) * 256 + t;
        if (idx >= 264192) return;
        ushort* buf = (idx >= 132096) ? y1t : xtt;
        int e_all = idx % 132096;
        int bq = e_all / 33024, e = e_all % 33024;
        int i, j, c;
        if (e < 8320)       { i = 0;   j = e >> 6; c = e & 63; }
        else if (e < 16640) { int e2 = e - 8320; i = 129; j = e2 >> 6; c = e2 & 63; }
        else                { int e2 = e - 16640; c = e2 & 63;
                              i = (e2 >> 7) + 1; j = ((e2 >> 6) & 1) ? 129 : 0; }
        buf[(size_t)bq * SLAB + (i * PADW + j) * 64 + c] = 0;
    }
}

// ---------------------------------------------------------------------------
// Fused layer, 32x32x16 fp16 MFMA, CSTRIDE-128 XOR-swizzled 15x23 window.
// 256 thr / 4 waves; 8x16-px patch; wave owns rows {2wv,2wv+1} x 16 = 32 px.
// s_setprio(1) wraps the phase-2 contraction: waves on a SIMD sit at
// different phases (no barriers in the main loop; independent blocks), so
// priority arbitration favors the MFMA/combine cluster (T5, attn-like case).
// ---------------------------------------------------------------------------
#define MF32(a,b,c) __builtin_amdgcn_mfma_f32_32x32x16_f16(a,b,c,0,0,0)

__global__ __launch_bounds__(256, 2) void fused(
    const ushort* __restrict__ xt, const ushort* __restrict__ wof,
    const float* __restrict__ bp, const float* __restrict__ bm,
    const ushort* __restrict__ wdf, const float* __restrict__ xres,
    float* __restrict__ outn, ushort* __restrict__ y1t, int mode)
{
    __shared__ __align__(16) char sm[SM_BYTES];
    const int t = threadIdx.x, l = t & 63, wv = t >> 6;
    const int lb = (blockIdx.x & 7) * 64 + (blockIdx.x >> 3);
    const int bb = lb >> 7;
    const int patch = lb & 127;
    const int i0 = (patch >> 3) * 8;
    const int j0 = (patch & 7) * 16;
    const int p  = l & 31;                   // lane's pixel
    const int h5 = l >> 5;                   // lane's k-half
    const ushort* xb = xt + (size_t)bb * SLAB;
    const char* xbb = (const char*)xb;

    // ---------- stage window (XOR chunk swizzle) ----------
    for (int s = t; s < NCELL * 8; s += 256) {
        int q = s & 7, cq = s >> 3;
        int c = cq % WC, r = cq / WC;
        int ip = min(max(i0 - 2 + r, 0), 129);
        int jp = min(max(j0 - 2 + c, 0), 129);
        uint4 v = *(const uint4*)(xbb + ((ip * PADW + jp) << 7) + (q << 4));
        *(uint4*)(sm + cq * CSTRIDE + ((q << 4) ^ hx16(cq))) = v;
    }
    __syncthreads();

    // ---------- phase 1: offset/mask conv (N=32, 36 MFMA) ----------
    f32x16 oacc = {0.f,0.f,0.f,0.f,0.f,0.f,0.f,0.f,0.f,0.f,0.f,0.f,0.f,0.f,0.f,0.f};
    {
        const int rbase = 2 * wv + (p >> 4) + 2;
        const int cbase = (p & 15) + 2;
        #pragma unroll
        for (int tap = 0; tap < 9; ++tap) {
            int ti = tap / 3, tj = tap - ti * 3;
            int ci = (rbase + ti) * WC + cbase + tj;
            const char* cell = sm + ci * CSTRIDE;
            int hb = hx16(ci);
            #pragma unroll
            for (int kb = 0; kb < 4; ++kb) {
                half8 b = *(const half8*)(wof + ((tap * 4 + kb) * 64 + l) * 8);
                half8 a = *(const half8*)(cell + (((kb * 2 + h5) << 4) ^ hb));
                oacc = MF32(a, b, oacc);
            }
        }
    }
    float* omS = (float*)(sm + OMS_OFF) + wv * 891;   // [27][33] per wave
    {
        int ch = l & 31;
        if (ch < 27) {
            float bias = (ch < 18) ? bp[ch] : bm[ch - 18];
            #pragma unroll
            for (int reg = 0; reg < 16; ++reg) {
                int m = (reg & 3) + 8 * (reg >> 2) + 4 * h5;
                float v = oacc[reg] + bias;
                if (ch >= 18) v = 1.f / (1.f + __expf(-v));
                omS[ch * 33 + m] = v;
            }
        }
    }

    // ---------- phase 2: coords pass, then wave-uniform branch ----------
    f32x16 acc0 = {0.f,0.f,0.f,0.f,0.f,0.f,0.f,0.f,0.f,0.f,0.f,0.f,0.f,0.f,0.f,0.f};
    f32x16 acc1 = acc0;
    const int irow = i0 + 2 * wv + (p >> 4), jcol = j0 + (p & 15);
    uint cpack[9]; float4 gw[9];
    bool okall = true;
    #pragma unroll
    for (int n = 0; n < 9; ++n) {
        int4 cc; float4 g;
        coords_tap_lds(omS, p, irow, jcol, n, cc, g);
        int rlt = cc.x - (i0 - 2), clt = cc.y - (j0 - 2);
        int rrb = cc.z - (i0 - 2), crb = cc.w - (j0 - 2);
        okall = okall & ((uint)rlt < (uint)WR) & ((uint)rrb < (uint)WR) &
                        ((uint)clt < (uint)WC) & ((uint)crb < (uint)WC);
        cpack[n] = (uint)(rlt & 255) | ((uint)(clt & 255) << 8) |
                   ((uint)(rrb & 255) << 16) | ((uint)(crb & 255) << 24);
        gw[n] = g;
    }

    __builtin_amdgcn_s_setprio(1);
    if (__all(okall)) {
        #pragma unroll
        for (int n = 0; n < 9; ++n) {
            uint cp_ = cpack[n];
            int rlt = cp_ & 255, clt = (cp_ >> 8) & 255;
            int rrb = (cp_ >> 16) & 255, crb = cp_ >> 24;
            int ciLT = rlt * WC + clt, ciRB = rrb * WC + crb;
            int ciLB = rlt * WC + crb, ciRT = rrb * WC + clt;
            const char* bLT = sm + ciLT * CSTRIDE;
            const char* bRB = sm + ciRB * CSTRIDE;
            const char* bLB = sm + ciLB * CSTRIDE;
            const char* bRT = sm + ciRT * CSTRIDE;
            int hLT = hx16(ciLT), hRB = hx16(ciRB);
            int hLB = hx16(ciLB), hRT = hx16(ciRT);
            float4 g = gw[n];
            const ushort* wb = wdf + (size_t)n * 4096 + l * 8;
            #pragma unroll
            for (int kb = 0; kb < 4; ++kb) {
                int qo = (kb * 2 + h5) << 4;
                half8 w0 = *(const half8*)(wb + (kb * 2 + 0) * 512);
                half8 w1 = *(const half8*)(wb + (kb * 2 + 1) * 512);
                half8 sLT = *(const half8*)(bLT + (qo ^ hLT));
                half8 sRB = *(const half8*)(bRB + (qo ^ hRB));
                half8 sLB = *(const half8*)(bLB + (qo ^ hLB));
                half8 sRT = *(const half8*)(bRT + (qo ^ hRT));
                half8 a = combine4h(sLT, sRB, sLB, sRT, g.x, g.y, g.z, g.w);
                acc0 = MF32(a, w0, acc0);
                acc1 = MF32(a, w1, acc1);
            }
        }
    } else {
        // dirty path: exact per-tap fallback (rare)
        #pragma unroll
        for (int n = 0; n < 9; ++n) {
            int4 cc; float4 g;
            coords_tap_lds(omS, p, irow, jcol, n, cc, g);
            int rlt = cc.x - (i0 - 2), clt = cc.y - (j0 - 2);
            int rrb = cc.z - (i0 - 2), crb = cc.w - (j0 - 2);
            bool ok = ((uint)rlt < (uint)WR) & ((uint)rrb < (uint)WR) &
                      ((uint)clt < (uint)WC) & ((uint)crb < (uint)WC);
            const ushort* wb = wdf + (size_t)n * 4096 + l * 8;
            #pragma unroll
            for (int kb = 0; kb < 4; ++kb) {
                int qo = (kb * 2 + h5) << 4;
                half8 w0 = *(const half8*)(wb + (kb * 2 + 0) * 512);
                half8 w1 = *(const half8*)(wb + (kb * 2 + 1) * 512);
                half8 sLT, sRB, sLB, sRT;
                if (ok) {
                    int ciLT = rlt * WC + clt, ciRB = rrb * WC + crb;
                    int ciLB = rlt * WC + crb, ciRT = rrb * WC + clt;
                    sLT = *(const half8*)(sm + ciLT * CSTRIDE + (qo ^ hx16(ciLT)));
                    sRB = *(const half8*)(sm + ciRB * CSTRIDE + (qo ^ hx16(ciRB)));
                    sLB = *(const half8*)(sm + ciLB * CSTRIDE + (qo ^ hx16(ciLB)));
                    sRT = *(const half8*)(sm + ciRT * CSTRIDE + (qo ^ hx16(ciRT)));
                } else {
                    sLT = *(const half8*)(xbb + (((cc.x * PADW + cc.y) << 7) + qo));
                    sRB = *(const half8*)(xbb + (((cc.z * PADW + cc.w) << 7) + qo));
                    sLB = *(const half8*)(xbb + (((cc.x * PADW + cc.w) << 7) + qo));
                    sRT = *(const half8*)(xbb + (((cc.z * PADW + cc.y) << 7) + qo));
                }
                half8 a = combine4h(sLT, sRB, sLB, sRT, g.x, g.y, g.z, g.w);
                acc0 = MF32(a, w0, acc0);
                acc1 = MF32(a, w1, acc1);
            }
        }
    }
    __builtin_amdgcn_s_setprio(0);

    // ---------- epilogue ----------
    if (mode == 0) {
        #pragma unroll
        for (int nt = 0; nt < 2; ++nt) {
            int oc = nt * 32 + (l & 31);
            const f32x16& av = nt ? acc1 : acc0;
            #pragma unroll
            for (int qd = 0; qd < 4; ++qd) {
                int m0 = 8 * qd + 4 * h5;
                int lr = m0 >> 4, col0 = m0 & 15;
                size_t o = ((size_t)(bb * 64 + oc)) * HWSZ +
                           (i0 + 2 * wv + lr) * 128 + j0 + col0;
                float4 rsd = *(const float4*)(xres + o);
                float4 vv;
                vv.x = av[qd * 4 + 0] + rsd.x; vv.y = av[qd * 4 + 1] + rsd.y;
                vv.z = av[qd * 4 + 2] + rsd.z; vv.w = av[qd * 4 + 3] + rsd.w;
                *(float4*)(outn + o) = vv;
            }
        }
    } else {
        // relu -> padded NHWC fp16, direct stores (lanes 0-31 = consecutive oc)
        ushort* yb = y1t + (size_t)bb * SLAB;
        #pragma unroll
        for (int nt = 0; nt < 2; ++nt) {
            int oc = nt * 32 + (l & 31);
            const f32x16& av = nt ? acc1 : acc0;
            #pragma unroll
            for (int reg = 0; reg < 16; ++reg) {
                int m = (reg & 3) + 8 * (reg >> 2) + 4 * h5;
                int ip = i0 + 2 * wv + (m >> 4) + 1;
                int jp = j0 + (m & 15) + 1;
                yb[(ip * PADW + jp) * 64 + oc] = f2hu(fmaxf(av[reg], 0.f));
            }
        }
    }
}

// ---------------------------------------------------------------------------
extern "C" void kernel_launch(void* const* d_in, const int* in_sizes, int n_in,
                              void* d_out, int out_size, void* d_ws, size_t ws_size,
                              hipStream_t stream)
{
    const float* x      = (const float*)d_in[0];
    const float* d1_w_p = (const float*)d_in[1];
    const float* d1_b_p = (const float*)d_in[2];
    const float* d1_w_m = (const float*)d_in[3];
    const float* d1_b_m = (const float*)d_in[4];
    const float* d1_w_c = (const float*)d_in[5];
    const float* d2_w_p = (const float*)d_in[6];
    const float* d2_b_p = (const float*)d_in[7];
    const float* d2_w_m = (const float*)d_in[8];
    const float* d2_b_m = (const float*)d_in[9];
    const float* d2_w_c = (const float*)d_in[10];
    float* out = (float*)d_out;

    char* ws = (char*)d_ws;
    ushort* xtt  = (ushort*)(ws);               //  8,652,800 B padded NHWC fp16 x
    ushort* y1t  = (ushort*)(ws + 8652800);     //  8,652,800 B padded NHWC fp16 y1
    ushort* wdf1 = (ushort*)(ws + 17305600);
    ushort* wof1 = (ushort*)(ws + 17379328);
    ushort* wdf2 = (ushort*)(ws + 17416192);
    ushort* wof2 = (ushort*)(ws + 17489920);

    prep<<<1592, 256, 0, stream>>>(x, xtt, y1t,
                                   d1_w_c, d1_w_p, d1_w_m, d2_w_c, d2_w_p, d2_w_m,
                                   wdf1, wof1, wdf2, wof2);

    fused<<<512, 256, 0, stream>>>(xtt, wof1, d1_b_p, d1_b_m, wdf1,
                                   nullptr, nullptr, y1t, 1);
    fused<<<512, 256, 0, stream>>>(y1t, wof2, d2_b_p, d2_b_m, wdf2,
                                   x, out, nullptr, 0);
}

// Round 19
// 63.416 us; speedup vs baseline: 1.1066x; 1.0020x over previous
//
#include <hip/hip_runtime.h>
#include <hip/hip_bf16.h>
#include <math.h>

typedef __attribute__((ext_vector_type(8))) _Float16 half8;
typedef __attribute__((ext_vector_type(16))) float f32x16;
typedef unsigned int uint;
typedef unsigned short ushort;

#define HWSZ 16384
#define PADW 130
#define SLAB (PADW*PADW*64)
// window: 15 rows x 23 cols of 128B cells at 128B stride, XOR chunk swizzle:
// chunk q of cell ci stored at slot q ^ hx(ci), hx = (ci ^ (ci>>3)) & 7.
#define WR 15
#define WC 23
#define NCELL (WR*WC)            // 345
#define CSTRIDE 128
#define OMS_OFF (NCELL*CSTRIDE)  // 44160
#define SM_BYTES (OMS_OFF + 4*27*33*4)   // 58416

__device__ __forceinline__ int hx16(int ci) {
    return ((ci ^ (ci >> 3)) & 7) << 4;
}
__device__ __forceinline__ ushort f2hu(float a) {
    _Float16 h = (_Float16)a; return *(ushort*)&h;
}
__device__ __forceinline__ uint pk2h(float a, float b) {
    _Float16 ha = (_Float16)a, hb = (_Float16)b;
    ushort ua = *(ushort*)&ha, ub = *(ushort*)&hb;
    return (uint)ua | ((uint)ub << 16);
}

// packed-fp16 bilinear combine (v_pk_fma_f16)
__device__ __forceinline__ half8 combine4h(half8 a0, half8 a1, half8 a2, half8 a3,
                                           float g0, float g1, float g2, float g3)
{
    _Float16 G0 = (_Float16)g0, G1 = (_Float16)g1;
    _Float16 G2 = (_Float16)g2, G3 = (_Float16)g3;
    return a0 * G0 + a1 * G1 + a2 * G2 + a3 * G3;
}

__device__ __forceinline__ void coords_tap_lds(
    const float* __restrict__ omS, int p, int irow, int jcol, int n,
    int4& cc, float4& bg)
{
    int di = n / 3, dj = n - di * 3;
    float offx = omS[n * 33 + p];
    float offy = omS[(9 + n) * 33 + p];
    float mv   = omS[(18 + n) * 33 + p];
    float pxf = (float)(irow + di) + offx;
    float pyf = (float)(jcol + dj) + offy;
    float fx = floorf(pxf), fy = floorf(pyf);
    float qltx = fminf(fmaxf(fx,       0.f), 129.f);
    float qlty = fminf(fmaxf(fy,       0.f), 129.f);
    float qrbx = fminf(fmaxf(fx + 1.f, 0.f), 129.f);
    float qrby = fminf(fmaxf(fy + 1.f, 0.f), 129.f);
    float pxc  = fminf(fmaxf(pxf,      0.f), 129.f);
    float pyc  = fminf(fmaxf(pyf,      0.f), 129.f);
    float glt = (1.f + (qltx - pxc)) * (1.f + (qlty - pyc));
    float grb = (1.f - (qrbx - pxc)) * (1.f - (qrby - pyc));
    float glb = (1.f + (qltx - pxc)) * (1.f - (qrby - pyc));
    float grt = (1.f - (qrbx - pxc)) * (1.f + (qlty - pyc));
    cc.x = (int)qltx; cc.y = (int)qlty; cc.z = (int)qrbx; cc.w = (int)qrby;
    bg.x = glt * mv; bg.y = grb * mv; bg.z = glb * mv; bg.w = grt * mv;
}

// ---------------------------------------------------------------------------
// prep: blocks [0,432): fragment-major fp16 weight buffers
//       blocks [432,560): NCHW fp32 -> padded NHWC fp16
//       blocks [560,1592): zero borders of xt and y1t
// ---------------------------------------------------------------------------
__global__ __launch_bounds__(256, 2) void prep(
    const float* __restrict__ x, ushort* __restrict__ xtt, ushort* __restrict__ y1t,
    const float* __restrict__ wc1, const float* __restrict__ wp1, const float* __restrict__ wm1,
    const float* __restrict__ wc2, const float* __restrict__ wp2, const float* __restrict__ wm2,
    ushort* __restrict__ wdf1, ushort* __restrict__ wof1,
    ushort* __restrict__ wdf2, ushort* __restrict__ wof2)
{
    int t = threadIdx.x;
    if (blockIdx.x < 432) {
        int idx0 = blockIdx.x * 256 + t;
        if (idx0 < 73728) {
            int lay = idx0 >= 36864;
            int idx = idx0 - lay * 36864;
            const float* wc = lay ? wc2 : wc1;
            ushort* dst = lay ? wdf2 : wdf1;
            int j = idx & 7, l = (idx >> 3) & 63;
            int nt = (idx >> 9) & 1, kb = (idx >> 10) & 3, tap = idx >> 12;
            int oc = nt * 32 + (l & 31);
            int c  = kb * 16 + ((l >> 5) << 3) + j;
            dst[idx] = f2hu(wc[(oc * 64 + c) * 9 + tap]);
        } else if (idx0 < 110592) {
            int r = idx0 - 73728;
            int lay = r >= 18432;
            int idx = r - lay * 18432;
            const float* wp = lay ? wp2 : wp1;
            const float* wm = lay ? wm2 : wm1;
            ushort* dst = lay ? wof2 : wof1;
            int j = idx & 7, l = (idx >> 3) & 63;
            int kb = (idx >> 9) & 3, tap = idx >> 11;
            int ch = l & 31;
            int c  = kb * 16 + ((l >> 5) << 3) + j;
            float v = 0.f;
            if (ch < 18)      v = wp[(ch * 64 + c) * 9 + tap];
            else if (ch < 27) v = wm[((ch - 18) * 64 + c) * 9 + tap];
            dst[idx] = f2hu(v);
        }
        return;
    }
    int bx = blockIdx.x - 432;
    int l = t & 63, wv = t >> 6;
    if (bx < 128) {
        int c2 = l & 31, ps = l >> 5;
        int pix0w = bx * 512 + wv * 128;
        int bq = pix0w >> 14;
        const float* xp0 = x + ((size_t)(bq * 64 + c2 * 2)) * HWSZ;
        ushort* xw = xtt + (size_t)bq * SLAB;
        #pragma unroll 8
        for (int p = 0; p < 64; ++p) {
            int pxi = (pix0w + p * 2 + ps) & (HWSZ - 1);
            int i = pxi >> 7, j = pxi & 127;
            uint u = pk2h(xp0[pxi], xp0[pxi + HWSZ]);
            *(uint*)(xw + ((i + 1) * PADW + (j + 1)) * 64 + c2 * 2) = u;
        }
    } else {
        int idx = (bx - 128) * 256 + t;
        if (idx >= 264192) return;
        ushort* buf = (idx >= 132096) ? y1t : xtt;
        int e_all = idx % 132096;
        int bq = e_all / 33024, e = e_all % 33024;
        int i, j, c;
        if (e < 8320)       { i = 0;   j = e >> 6; c = e & 63; }
        else if (e < 16640) { int e2 = e - 8320; i = 129; j = e2 >> 6; c = e2 & 63; }
        else                { int e2 = e - 16640; c = e2 & 63;
                              i = (e2 >> 7) + 1; j = ((e2 >> 6) & 1) ? 129 : 0; }
        buf[(size_t)bq * SLAB + (i * PADW + j) * 64 + c] = 0;
    }
}

// ---------------------------------------------------------------------------
// Fused layer, 32x32x16 fp16 MFMA, CSTRIDE-128 XOR-swizzled 15x23 window.
// 256 thr / 4 waves; 8x16-px patch; wave owns rows {2wv,2wv+1} x 16 = 32 px.
// ---------------------------------------------------------------------------
#define MF32(a,b,c) __builtin_amdgcn_mfma_f32_32x32x16_f16(a,b,c,0,0,0)

__global__ __launch_bounds__(256, 2) void fused(
    const ushort* __restrict__ xt, const ushort* __restrict__ wof,
    const float* __restrict__ bp, const float* __restrict__ bm,
    const ushort* __restrict__ wdf, const float* __restrict__ xres,
    float* __restrict__ outn, ushort* __restrict__ y1t, int mode)
{
    __shared__ __align__(16) char sm[SM_BYTES];
    const int t = threadIdx.x, l = t & 63, wv = t >> 6;
    const int lb = (blockIdx.x & 7) * 64 + (blockIdx.x >> 3);
    const int bb = lb >> 7;
    const int patch = lb & 127;
    const int i0 = (patch >> 3) * 8;
    const int j0 = (patch & 7) * 16;
    const int p  = l & 31;                   // lane's pixel
    const int h5 = l >> 5;                   // lane's k-half
    const ushort* xb = xt + (size_t)bb * SLAB;
    const char* xbb = (const char*)xb;

    // ---------- stage window (XOR chunk swizzle) ----------
    for (int s = t; s < NCELL * 8; s += 256) {
        int q = s & 7, cq = s >> 3;
        int c = cq % WC, r = cq / WC;
        int ip = min(max(i0 - 2 + r, 0), 129);
        int jp = min(max(j0 - 2 + c, 0), 129);
        uint4 v = *(const uint4*)(xbb + ((ip * PADW + jp) << 7) + (q << 4));
        *(uint4*)(sm + cq * CSTRIDE + ((q << 4) ^ hx16(cq))) = v;
    }
    __syncthreads();

    // ---------- phase 1: offset/mask conv (N=32, 36 MFMA) ----------
    f32x16 oacc = {0.f,0.f,0.f,0.f,0.f,0.f,0.f,0.f,0.f,0.f,0.f,0.f,0.f,0.f,0.f,0.f};
    {
        const int rbase = 2 * wv + (p >> 4) + 2;
        const int cbase = (p & 15) + 2;
        #pragma unroll
        for (int tap = 0; tap < 9; ++tap) {
            int ti = tap / 3, tj = tap - ti * 3;
            int ci = (rbase + ti) * WC + cbase + tj;
            const char* cell = sm + ci * CSTRIDE;
            int hb = hx16(ci);
            #pragma unroll
            for (int kb = 0; kb < 4; ++kb) {
                half8 b = *(const half8*)(wof + ((tap * 4 + kb) * 64 + l) * 8);
                half8 a = *(const half8*)(cell + (((kb * 2 + h5) << 4) ^ hb));
                oacc = MF32(a, b, oacc);
            }
        }
    }
    float* omS = (float*)(sm + OMS_OFF) + wv * 891;   // [27][33] per wave
    {
        int ch = l & 31;
        if (ch < 27) {
            float bias = (ch < 18) ? bp[ch] : bm[ch - 18];
            #pragma unroll
            for (int reg = 0; reg < 16; ++reg) {
                int m = (reg & 3) + 8 * (reg >> 2) + 4 * h5;
                float v = oacc[reg] + bias;
                if (ch >= 18) v = 1.f / (1.f + __expf(-v));
                omS[ch * 33 + m] = v;
            }
        }
    }

    // ---------- phase 2: coords pass, then wave-uniform branch ----------
    f32x16 acc0 = {0.f,0.f,0.f,0.f,0.f,0.f,0.f,0.f,0.f,0.f,0.f,0.f,0.f,0.f,0.f,0.f};
    f32x16 acc1 = acc0;
    const int irow = i0 + 2 * wv + (p >> 4), jcol = j0 + (p & 15);
    uint cpack[9]; float4 gw[9];
    bool okall = true;
    #pragma unroll
    for (int n = 0; n < 9; ++n) {
        int4 cc; float4 g;
        coords_tap_lds(omS, p, irow, jcol, n, cc, g);
        int rlt = cc.x - (i0 - 2), clt = cc.y - (j0 - 2);
        int rrb = cc.z - (i0 - 2), crb = cc.w - (j0 - 2);
        okall = okall & ((uint)rlt < (uint)WR) & ((uint)rrb < (uint)WR) &
                        ((uint)clt < (uint)WC) & ((uint)crb < (uint)WC);
        cpack[n] = (uint)(rlt & 255) | ((uint)(clt & 255) << 8) |
                   ((uint)(rrb & 255) << 16) | ((uint)(crb & 255) << 24);
        gw[n] = g;
    }

    __builtin_amdgcn_s_setprio(1);
    if (__all(okall)) {
        #pragma unroll
        for (int n = 0; n < 9; ++n) {
            uint cp_ = cpack[n];
            int rlt = cp_ & 255, clt = (cp_ >> 8) & 255;
            int rrb = (cp_ >> 16) & 255, crb = cp_ >> 24;
            int ciLT = rlt * WC + clt, ciRB = rrb * WC + crb;
            int ciLB = rlt * WC + crb, ciRT = rrb * WC + clt;
            const char* bLT = sm + ciLT * CSTRIDE;
            const char* bRB = sm + ciRB * CSTRIDE;
            const char* bLB = sm + ciLB * CSTRIDE;
            const char* bRT = sm + ciRT * CSTRIDE;
            int hLT = hx16(ciLT), hRB = hx16(ciRB);
            int hLB = hx16(ciLB), hRT = hx16(ciRT);
            float4 g = gw[n];
            const ushort* wb = wdf + (size_t)n * 4096 + l * 8;
            #pragma unroll
            for (int kb = 0; kb < 4; ++kb) {
                int qo = (kb * 2 + h5) << 4;
                half8 w0 = *(const half8*)(wb + (kb * 2 + 0) * 512);
                half8 w1 = *(const half8*)(wb + (kb * 2 + 1) * 512);
                half8 sLT = *(const half8*)(bLT + (qo ^ hLT));
                half8 sRB = *(const half8*)(bRB + (qo ^ hRB));
                half8 sLB = *(const half8*)(bLB + (qo ^ hLB));
                half8 sRT = *(const half8*)(bRT + (qo ^ hRT));
                half8 a = combine4h(sLT, sRB, sLB, sRT, g.x, g.y, g.z, g.w);
                acc0 = MF32(a, w0, acc0);
                acc1 = MF32(a, w1, acc1);
            }
        }
    } else {
        // dirty path: exact per-tap fallback (rare)
        #pragma unroll
        for (int n = 0; n < 9; ++n) {
            int4 cc; float4 g;
            coords_tap_lds(omS, p, irow, jcol, n, cc, g);
            int rlt = cc.x - (i0 - 2), clt = cc.y - (j0 - 2);
            int rrb = cc.z - (i0 - 2), crb = cc.w - (j0 - 2);
            bool ok = ((uint)rlt < (uint)WR) & ((uint)rrb < (uint)WR) &
                      ((uint)clt < (uint)WC) & ((uint)crb < (uint)WC);
            const ushort* wb = wdf + (size_t)n * 4096 + l * 8;
            #pragma unroll
            for (int kb = 0; kb < 4; ++kb) {
                int qo = (kb * 2 + h5) << 4;
                half8 w0 = *(const half8*)(wb + (kb * 2 + 0) * 512);
                half8 w1 = *(const half8*)(wb + (kb * 2 + 1) * 512);
                half8 sLT, sRB, sLB, sRT;
                if (ok) {
                    int ciLT = rlt * WC + clt, ciRB = rrb * WC + crb;
                    int ciLB = rlt * WC + crb, ciRT = rrb * WC + clt;
                    sLT = *(const half8*)(sm + ciLT * CSTRIDE + (qo ^ hx16(ciLT)));
                    sRB = *(const half8*)(sm + ciRB * CSTRIDE + (qo ^ hx16(ciRB)));
                    sLB = *(const half8*)(sm + ciLB * CSTRIDE + (qo ^ hx16(ciLB)));
                    sRT = *(const half8*)(sm + ciRT * CSTRIDE + (qo ^ hx16(ciRT)));
                } else {
                    sLT = *(const half8*)(xbb + (((cc.x * PADW + cc.y) << 7) + qo));
                    sRB = *(const half8*)(xbb + (((cc.z * PADW + cc.w) << 7) + qo));
                    sLB = *(const half8*)(xbb + (((cc.x * PADW + cc.w) << 7) + qo));
                    sRT = *(const half8*)(xbb + (((cc.z * PADW + cc.y) << 7) + qo));
                }
                half8 a = combine4h(sLT, sRB, sLB, sRT, g.x, g.y, g.z, g.w);
                acc0 = MF32(a, w0, acc0);
                acc1 = MF32(a, w1, acc1);
            }
        }
    }
    __builtin_amdgcn_s_setprio(0);

    // ---------- epilogue ----------
    if (mode == 0) {
        #pragma unroll
        for (int nt = 0; nt < 2; ++nt) {
            int oc = nt * 32 + (l & 31);
            const f32x16& av = nt ? acc1 : acc0;
            #pragma unroll
            for (int qd = 0; qd < 4; ++qd) {
                int m0 = 8 * qd + 4 * h5;
                int lr = m0 >> 4, col0 = m0 & 15;
                size_t o = ((size_t)(bb * 64 + oc)) * HWSZ +
                           (i0 + 2 * wv + lr) * 128 + j0 + col0;
                float4 rsd = *(const float4*)(xres + o);
                float4 vv;
                vv.x = av[qd * 4 + 0] + rsd.x; vv.y = av[qd * 4 + 1] + rsd.y;
                vv.z = av[qd * 4 + 2] + rsd.z; vv.w = av[qd * 4 + 3] + rsd.w;
                *(float4*)(outn + o) = vv;
            }
        }
    } else {
        // relu -> padded NHWC fp16, direct stores (lanes 0-31 = consecutive oc)
        ushort* yb = y1t + (size_t)bb * SLAB;
        #pragma unroll
        for (int nt = 0; nt < 2; ++nt) {
            int oc = nt * 32 + (l & 31);
            const f32x16& av = nt ? acc1 : acc0;
            #pragma unroll
            for (int reg = 0; reg < 16; ++reg) {
                int m = (reg & 3) + 8 * (reg >> 2) + 4 * h5;
                int ip = i0 + 2 * wv + (m >> 4) + 1;
                int jp = j0 + (m & 15) + 1;
                yb[(ip * PADW + jp) * 64 + oc] = f2hu(fmaxf(av[reg], 0.f));
            }
        }
    }
}

// ---------------------------------------------------------------------------
extern "C" void kernel_launch(void* const* d_in, const int* in_sizes, int n_in,
                              void* d_out, int out_size, void* d_ws, size_t ws_size,
                              hipStream_t stream)
{
    const float* x      = (const float*)d_in[0];
    const float* d1_w_p = (const float*)d_in[1];
    const float* d1_b_p = (const float*)d_in[2];
    const float* d1_w_m = (const float*)d_in[3];
    const float* d1_b_m = (const float*)d_in[4];
    const float* d1_w_c = (const float*)d_in[5];
    const float* d2_w_p = (const float*)d_in[6];
    const float* d2_b_p = (const float*)d_in[7];
    const float* d2_w_m = (const float*)d_in[8];
    const float* d2_b_m = (const float*)d_in[9];
    const float* d2_w_c = (const float*)d_in[10];
    float* out = (float*)d_out;

    char* ws = (char*)d_ws;
    ushort* xtt  = (ushort*)(ws);               //  8,652,800 B padded NHWC fp16 x
    ushort* y1t  = (ushort*)(ws + 8652800);     //  8,652,800 B padded NHWC fp16 y1
    ushort* wdf1 = (ushort*)(ws + 17305600);
    ushort* wof1 = (ushort*)(ws + 17379328);
    ushort* wdf2 = (ushort*)(ws + 17416192);
    ushort* wof2 = (ushort*)(ws + 17489920);

    prep<<<1592, 256, 0, stream>>>(x, xtt, y1t,
                                   d1_w_c, d1_w_p, d1_w_m, d2_w_c, d2_w_p, d2_w_m,
                                   wdf1, wof1, wdf2, wof2);

    fused<<<512, 256, 0, stream>>>(xtt, wof1, d1_b_p, d1_b_m, wdf1,
                                   nullptr, nullptr, y1t, 1);
    fused<<<512, 256, 0, stream>>>(y1t, wof2, d2_b_p, d2_b_m, wdf2,
                                   x, out, nullptr, 0);
}